// Round 17
// baseline (387.625 us; speedup 1.0000x reference)
//
#include <hip/hip_runtime.h>
#include <hip/hip_bf16.h>

typedef __attribute__((ext_vector_type(4))) float f32x4;
typedef __attribute__((ext_vector_type(8))) short bf16x8;

#define NR 12288
#define HD 256
#define TAU 0.5f
#define NU 24576              // unified rows (n1;n2)
#define NTT 192               // 128-row tiles per dim of unified matrix
#define NSUB 384              // partial-sum slots (fp32) — fully covered, no memset needed
#define NBLK (NTT * (NTT + 1) / 2)   // 18528 = 8 * 2316
#define LAM 1.69864368f       // sqrt(log2(e)/TAU); gram acc = sim*log2e/tau directly

__device__ __forceinline__ unsigned short f2bf(float f) {
    unsigned int x = __builtin_bit_cast(unsigned int, f);
    x += 0x7fffu + ((x >> 16) & 1u);
    return (unsigned short)(x >> 16);
}

// manual OCP e4m3fn cast, RNE in normal range, step-round in denormal range
__device__ __forceinline__ unsigned char f2e4m3(float f) {
    unsigned int u = __builtin_bit_cast(unsigned int, f);
    unsigned int s = (u >> 24) & 0x80u;
    float af = fabsf(f);
    if (af >= 464.f) return (unsigned char)(s | 0x7Eu);      // saturate to 448
    if (af < 0.015625f) {                                    // denormal: step 2^-9
        unsigned int q = (unsigned int)(af * 512.f + 0.5f);
        return (unsigned char)(s | q);
    }
    int e = (int)((u >> 23) & 0xffu) - 127;
    unsigned int mant = u & 0x7fffffu;
    unsigned int val = (unsigned int)((e + 7) << 3) | (mant >> 20);
    unsigned int rem = mant & 0xfffffu;
    val += (rem > 0x80000u) || (rem == 0x80000u && (val & 1u));
    return (unsigned char)(s | val);
}

// sum over each 16-lane group via 4 DPP adds — pure VALU, zero LDS-pipe traffic.
__device__ __forceinline__ float row16_sum(float x) {
    int v;
    v = __builtin_amdgcn_update_dpp(0, __builtin_bit_cast(int, x), 0xB1, 0xF, 0xF, true);
    x += __builtin_bit_cast(float, v);
    v = __builtin_amdgcn_update_dpp(0, __builtin_bit_cast(int, x), 0x4E, 0xF, 0xF, true);
    x += __builtin_bit_cast(float, v);
    v = __builtin_amdgcn_update_dpp(0, __builtin_bit_cast(int, x), 0x141, 0xF, 0xF, true);
    x += __builtin_bit_cast(float, v);
    v = __builtin_amdgcn_update_dpp(0, __builtin_bit_cast(int, x), 0x140, 0xF, 0xF, true);
    x += __builtin_bit_cast(float, v);
    return x;
}

// load 8 consecutive f32 and round-to-nearest-even pack into bf16x8 (verified in R11/R12)
__device__ __forceinline__ bf16x8 cvt8(const float* __restrict__ p) {
    float4 a = *(const float4*)p;
    float4 b = *(const float4*)(p + 4);
    union { unsigned int i[4]; bf16x8 v; } u;
    u.i[0] = ((unsigned int)f2bf(a.y) << 16) | f2bf(a.x);
    u.i[1] = ((unsigned int)f2bf(a.w) << 16) | f2bf(a.z);
    u.i[2] = ((unsigned int)f2bf(b.y) << 16) | f2bf(b.x);
    u.i[3] = ((unsigned int)f2bf(b.w) << 16) | f2bf(b.z);
    return u.v;
}

// ---------- both W transposes in one launch: grid (HD, 2) ----------
__global__ __launch_bounds__(256) void transpose_cast_kernel(const float* __restrict__ W1,
                                                             const float* __restrict__ W2,
                                                             unsigned short* __restrict__ W1t,
                                                             unsigned short* __restrict__ W2t) {
    const float* W = blockIdx.y ? W2 : W1;
    unsigned short* Wt = blockIdx.y ? W2t : W1t;
    int n = blockIdx.x;
    int k = threadIdx.x;
    Wt[n * HD + k] = f2bf(W[k * HD + n]);
}

// ---------- projA: z (f32, cast in-register) @ W1t^T + b1, ELU -> t (bf16). grid (192, 2) ----------
__global__ __launch_bounds__(256) void projA_kernel(const float* __restrict__ z1,
                                                    const float* __restrict__ z2,
                                                    const unsigned short* __restrict__ W1t,
                                                    const float* __restrict__ b1,
                                                    unsigned short* __restrict__ t1,
                                                    unsigned short* __restrict__ t2) {
    const float* A = blockIdx.y ? z2 : z1;
    unsigned short* C = blockIdx.y ? t2 : t1;
    const int lane = threadIdx.x & 63;
    const int wave = threadIdx.x >> 6;
    const int row0 = blockIdx.x * 64;
    const int col0 = wave * 64;
    const int lr = lane & 15, lk = lane >> 4;

    f32x4 acc[4][4] = {};
    const unsigned short* Bb = W1t + (size_t)(col0 + lr) * HD + lk * 8;
#pragma unroll
    for (int k0 = 0; k0 < HD; k0 += 32) {
        bf16x8 af[4], bfr[4];
#pragma unroll
        for (int m = 0; m < 4; ++m)
            af[m] = cvt8(A + (size_t)(row0 + m * 16 + lr) * HD + k0 + lk * 8);
#pragma unroll
        for (int n = 0; n < 4; ++n) bfr[n] = *(const bf16x8*)(Bb + n * 16 * HD + k0);
#pragma unroll
        for (int m = 0; m < 4; ++m)
#pragma unroll
            for (int n = 0; n < 4; ++n)
                acc[m][n] = __builtin_amdgcn_mfma_f32_16x16x32_bf16(af[m], bfr[n], acc[m][n], 0, 0, 0);
    }
#pragma unroll
    for (int m = 0; m < 4; ++m) {
#pragma unroll
        for (int n = 0; n < 4; ++n) {
            int col = col0 + n * 16 + lr;
            float b = b1[col];
#pragma unroll
            for (int r = 0; r < 4; ++r) {
                int row = row0 + m * 16 + lk * 4 + r;
                float v = acc[m][n][r] + b;
                v = v > 0.f ? v : expm1f(v);
                C[(size_t)row * HD + col] = f2bf(v);
            }
        }
    }
}

// ---------- projB: t (bf16) @ W2t^T + b2 -> h (f32). grid (192, 2) ----------
__global__ __launch_bounds__(256) void projB_kernel(const unsigned short* __restrict__ t1,
                                                    const unsigned short* __restrict__ t2,
                                                    const unsigned short* __restrict__ W2t,
                                                    const float* __restrict__ b2,
                                                    float* __restrict__ h1,
                                                    float* __restrict__ h2) {
    const unsigned short* A = blockIdx.y ? t2 : t1;
    float* C = blockIdx.y ? h2 : h1;
    const int lane = threadIdx.x & 63;
    const int wave = threadIdx.x >> 6;
    const int row0 = blockIdx.x * 64;
    const int col0 = wave * 64;
    const int lr = lane & 15, lk = lane >> 4;

    f32x4 acc[4][4] = {};
    const unsigned short* Ab = A + (size_t)(row0 + lr) * HD + lk * 8;
    const unsigned short* Bb = W2t + (size_t)(col0 + lr) * HD + lk * 8;
#pragma unroll
    for (int k0 = 0; k0 < HD; k0 += 32) {
        bf16x8 af[4], bfr[4];
#pragma unroll
        for (int m = 0; m < 4; ++m) af[m] = *(const bf16x8*)(Ab + m * 16 * HD + k0);
#pragma unroll
        for (int n = 0; n < 4; ++n) bfr[n] = *(const bf16x8*)(Bb + n * 16 * HD + k0);
#pragma unroll
        for (int m = 0; m < 4; ++m)
#pragma unroll
            for (int n = 0; n < 4; ++n)
                acc[m][n] = __builtin_amdgcn_mfma_f32_16x16x32_bf16(af[m], bfr[n], acc[m][n], 0, 0, 0);
    }
#pragma unroll
    for (int m = 0; m < 4; ++m) {
#pragma unroll
        for (int n = 0; n < 4; ++n) {
            int col = col0 + n * 16 + lr;
            float b = b2[col];
#pragma unroll
            for (int r = 0; r < 4; ++r) {
                int row = row0 + m * 16 + lk * 4 + r;
                C[(size_t)row * HD + col] = acc[m][n][r] + b;
            }
        }
    }
}

// ---------- normalize rows (fp32) -> fp8 e4m3 (LAM-scaled) into unified buffer + dvec ----------
// nU8 layout: the two 8B halves of every 16B chunk are SWAPPED for rows with bit3 set
// (store addr ^= ((row>>3)&1)<<3) — pre-bakes the LDS bank half-swap for conflict-free b64 reads.
__global__ __launch_bounds__(256) void norm_diag_kernel(const float* __restrict__ h1,
                                                        const float* __restrict__ h2,
                                                        unsigned char* __restrict__ n1,
                                                        unsigned char* __restrict__ n2,
                                                        float* __restrict__ dvec) {
    const int lane = threadIdx.x & 63;
    const int wave = threadIdx.x >> 6;
    const int row = blockIdx.x * 4 + wave;
    const float4 a = *(const float4*)(h1 + (size_t)row * HD + lane * 4);
    const float4 b = *(const float4*)(h2 + (size_t)row * HD + lane * 4);
    float sa = a.x * a.x + a.y * a.y + a.z * a.z + a.w * a.w;
    float sb = b.x * b.x + b.y * b.y + b.z * b.z + b.w * b.w;
    float sab = a.x * b.x + a.y * b.y + a.z * b.z + a.w * b.w;
#pragma unroll
    for (int m = 32; m; m >>= 1) {
        sa += __shfl_xor(sa, m);
        sb += __shfl_xor(sb, m);
        sab += __shfl_xor(sab, m);
    }
    float na = sqrtf(sa); na = na > 1e-12f ? na : 1e-12f;
    float nb = sqrtf(sb); nb = nb > 1e-12f ? nb : 1e-12f;
    float ia = 1.f / na, ib = 1.f / nb;
    float sca = ia * LAM, scb = ib * LAM;
    uchar4 q1, q2;
    q1.x = f2e4m3(a.x * sca); q1.y = f2e4m3(a.y * sca); q1.z = f2e4m3(a.z * sca); q1.w = f2e4m3(a.w * sca);
    q2.x = f2e4m3(b.x * scb); q2.y = f2e4m3(b.y * scb); q2.z = f2e4m3(b.z * scb); q2.w = f2e4m3(b.w * scb);
    const int sw = ((row >> 3) & 1) << 3;                    // half-swap by row bit3
    *(uchar4*)(n1 + (size_t)row * HD + ((lane * 4) ^ sw)) = q1;
    *(uchar4*)(n2 + (size_t)row * HD + ((lane * 4) ^ sw)) = q2;
    if (lane == 0) dvec[row] = sab * ia * ib * (1.f / TAU);
}

// ---------- unified symmetric Gram (fp8): upper-tri 128x128 tiles of exp2(M@M^T) ----------
// R17: B-panel-only LDS (32 KB) + per-ks A-fragment streaming from global with +1-step
// register prefetch (aNxt while aCur computes; only 16 VGPRs of A-state, unlike R13's
// 64-VGPR upfront block). launch_bounds(256,4) -> 4 blocks/CU = 4 waves/SIMD: doubles the
// independent issue streams on the saturated SIMD port (R16 diagnosis: MFMA+VALU ~ full
// issue at 2 waves/SIMD). A addressing formula is R13's (correctness-verified); B staging,
// swizzle, epilogue, RPART slots are R15 verbatim.
__global__ __launch_bounds__(256, 4) void gram_kernel(const unsigned char* __restrict__ nU8,
                                                      float* __restrict__ RPART) {
    __shared__ __align__(16) unsigned char lB[128 * 256];  // 32KB — B panel only

    const int bid = blockIdx.x;
    const int t0 = (bid & 7) * (NBLK / 8) + (bid >> 3);
    int i = (int)((385.f - sqrtf((float)(385 * 385 - 8 * t0))) * 0.5f);
    if (i < 0) i = 0;
    if (i > NTT - 1) i = NTT - 1;
    while (i > 0 && i * NTT - i * (i - 1) / 2 > t0) --i;
    while ((i + 1) * NTT - (i + 1) * i / 2 <= t0) ++i;
    const int j = i + (t0 - (i * NTT - i * (i - 1) / 2));
    const bool diag = (i == j);

    const unsigned char* X = nU8 + (size_t)i * 128 * HD;
    const unsigned char* Y = nU8 + (size_t)j * 128 * HD;

    const int t = threadIdx.x;
    const int lane = t & 63;
    const int wave = t >> 6;
    const int wr = wave >> 1, wc = wave & 1;      // 2x2 wave grid; wave tile 64x64
    const int lr = lane & 15, lk = lane >> 4;
    const int hswap = (lr >> 3) & 1;              // row bit3 (uniform across frags)

    // ---- stage B panel into LDS (pre-swizzled source chunks; R15 verbatim) ----
    {
        const int rbase = t >> 4;                              // 0..15
        const int schunk = (t & 15) ^ rbase;                   // pre-swizzled source slot
        const unsigned char* gy = (diag ? X : Y) + rbase * 256 + schunk * 16;
#pragma unroll
        for (int c = 0; c < 8; ++c) {
            __builtin_amdgcn_global_load_lds(
                (const __attribute__((address_space(1))) unsigned int*)(gy + c * 4096),
                (__attribute__((address_space(3))) unsigned int*)(&lB[c * 4096 + t * 16]),
                16, 0, 0);
        }
    }

    // A stream base (R13-verified formula): row = wr*64 + m*16 + lr; the 8B k-group at
    // cols ks*32 + lk*8 lives at byte (col ^ (hswap*8)) due to the baked half-swap.
    const unsigned char* Abase = X + (size_t)(wr * 64 + lr) * 256 + ((lk * 8) ^ (hswap * 8));

    long aCur[4], aNxt[4];
#pragma unroll
    for (int m = 0; m < 4; ++m)
        aCur[m] = *(const long*)(Abase + m * 16 * 256);        // ks=0 prefetch

    __syncthreads();   // drains B staging (+ ks0 A loads); the ONLY full barrier

    f32x4 acc[4][4] = {};
    const unsigned char* sB = lB + (size_t)(wc * 64 + lr) * 256 + ((lk & 1) ^ hswap) * 8;

#pragma unroll
    for (int ks = 0; ks < 8; ++ks) {
        if (ks < 7) {
#pragma unroll
            for (int m = 0; m < 4; ++m)
                aNxt[m] = *(const long*)(Abase + m * 16 * 256 + (ks + 1) * 32);
        }
        const int chnk = ((2 * ks + (lk >> 1)) ^ lr) * 16;     // swizzled 16B chunk
        long bfr[4];
#pragma unroll
        for (int n = 0; n < 4; ++n)
            bfr[n] = *(const long*)(sB + n * 16 * 256 + chnk);
#pragma unroll
        for (int m = 0; m < 4; ++m)
#pragma unroll
            for (int n = 0; n < 4; ++n)
                acc[m][n] = __builtin_amdgcn_mfma_f32_16x16x32_fp8_fp8(aCur[m], bfr[n], acc[m][n], 0, 0, 0);
#pragma unroll
        for (int m = 0; m < 4; ++m) aCur[m] = aNxt[m];
    }

#pragma unroll
    for (int m = 0; m < 4; ++m)
#pragma unroll
        for (int n = 0; n < 4; ++n)
#pragma unroll
            for (int r = 0; r < 4; ++r)
                acc[m][n][r] = exp2f(acc[m][n][r]);    // LAM pre-fold: acc already sim*log2e/tau

    // rowsum partials (DPP, VALU-only)
    {
        float* dst = RPART + (size_t)(2 * j + wc) * NU + i * 128 + wr * 64;
#pragma unroll
        for (int m = 0; m < 4; ++m) {
#pragma unroll
            for (int r = 0; r < 4; ++r) {
                float rs = (acc[m][0][r] + acc[m][1][r]) + (acc[m][2][r] + acc[m][3][r]);
                rs = row16_sum(rs);
                if (lr == 0) dst[m * 16 + lk * 4 + r] = rs;
            }
        }
    }
    // colsum partials (off-diag)
    if (!diag) {
        float* dst = RPART + (size_t)(2 * i + wr) * NU + j * 128 + wc * 64;
#pragma unroll
        for (int n = 0; n < 4; ++n) {
            float cs = 0.f;
#pragma unroll
            for (int m = 0; m < 4; ++m)
#pragma unroll
                for (int r = 0; r < 4; ++r) cs += acc[m][n][r];
            cs += __shfl_xor(cs, 16);
            cs += __shfl_xor(cs, 32);
            if (lk == 0) dst[n * 16 + lr] = cs;
        }
    }
}

// ---------- fused reduce + loss (verified R11/R12): S terms from RPART, log-loss, partials ----------
__global__ __launch_bounds__(128) void loss_sum_kernel(const float* __restrict__ RPART,
                                                       const float* __restrict__ dvec,
                                                       float* __restrict__ partial) {
    const int i = blockIdx.x * 128 + threadIdx.x;
    float s1 = 0.f, s2 = 0.f;
#pragma unroll 8
    for (int p = 0; p < NSUB; ++p) {
        s1 += RPART[(size_t)p * NU + i];
        s2 += RPART[(size_t)p * NU + NR + i];
    }
    const float e2 = 7.389056099f;  // exp(1/tau)
    float v = 0.5f * (logf(s1 - e2) + logf(s2 - e2)) - dvec[i];
#pragma unroll
    for (int m = 32; m; m >>= 1) v += __shfl_xor(v, m);
    __shared__ float wsum[2];
    if ((threadIdx.x & 63) == 0) wsum[threadIdx.x >> 6] = v;
    __syncthreads();
    if (threadIdx.x == 0) partial[blockIdx.x] = wsum[0] + wsum[1];
}

__global__ __launch_bounds__(128) void loss_final_kernel(const float* __restrict__ partial,
                                                         float* __restrict__ out, int nb) {
    float s = 0.f;
    for (int i = threadIdx.x; i < nb; i += 128) s += partial[i];
#pragma unroll
    for (int m = 32; m; m >>= 1) s += __shfl_xor(s, m);
    __shared__ float wsum[2];
    if ((threadIdx.x & 63) == 0) wsum[threadIdx.x >> 6] = s;
    __syncthreads();
    if (threadIdx.x == 0) out[0] = (wsum[0] + wsum[1]) * (1.f / (float)NR);
}

extern "C" void kernel_launch(void* const* d_in, const int* in_sizes, int n_in,
                              void* d_out, int out_size, void* d_ws, size_t ws_size,
                              hipStream_t stream) {
    const float* z1 = (const float*)d_in[0];
    const float* z2 = (const float*)d_in[1];
    const float* W1 = (const float*)d_in[2];
    const float* b1 = (const float*)d_in[3];
    const float* W2 = (const float*)d_in[4];
    const float* b2 = (const float*)d_in[5];

    char* ws = (char*)d_ws;
    size_t off = 0;
    auto alloc = [&](size_t bytes) {
        void* p = ws + off;
        off += (bytes + 255) & ~(size_t)255;
        return p;
    };
    const size_t NH2 = (size_t)NR * HD * 2;  // bf16 matrix bytes (6.29 MB)
    // Dead-by-gram-time prefix (t1,t2,W,h1,h2 = 38.01 MB) is aliased by RPART (37.75 MB).
    unsigned short* t1 = (unsigned short*)alloc(NH2);
    unsigned short* t2 = (unsigned short*)alloc(NH2);
    unsigned short* W1t = (unsigned short*)alloc(HD * HD * 2);
    unsigned short* W2t = (unsigned short*)alloc(HD * HD * 2);
    float* h1 = (float*)alloc((size_t)NR * HD * 4);
    float* h2 = (float*)alloc((size_t)NR * HD * 4);
    unsigned char* nU = (unsigned char*)alloc((size_t)NU * HD);   // fp8, LAM-scaled (live)
    float* dvec = (float*)alloc(NR * 4);                          // live
    float* partial = (float*)alloc(96 * 4);                       // live
    float* RPART = (float*)ws;  // 384*24576*4 = 37,748,736 B < nU offset (38,010,880)

    transpose_cast_kernel<<<dim3(HD, 2), 256, 0, stream>>>(W1, W2, W1t, W2t);

    projA_kernel<<<dim3(NR / 64, 2), 256, 0, stream>>>(z1, z2, W1t, b1, t1, t2);
    projB_kernel<<<dim3(NR / 64, 2), 256, 0, stream>>>(t1, t2, W2t, b2, h1, h2);

    norm_diag_kernel<<<NR / 4, 256, 0, stream>>>(h1, h2, nU, nU + (size_t)NR * HD, dvec);

    gram_kernel<<<NBLK, 256, 0, stream>>>(nU, RPART);

    loss_sum_kernel<<<NR / 128, 128, 0, stream>>>(RPART, dvec, partial);
    loss_final_kernel<<<1, 128, 0, stream>>>(partial, (float*)d_out, NR / 128);
}

// Round 18
// 253.773 us; speedup vs baseline: 1.5274x; 1.5274x over previous
//
#include <hip/hip_runtime.h>
#include <hip/hip_bf16.h>

typedef __attribute__((ext_vector_type(4))) float f32x4;
typedef __attribute__((ext_vector_type(8))) short bf16x8;

#define NR 12288
#define HD 256
#define TAU 0.5f
#define NU 24576              // unified rows (n1;n2)
#define NTT 192               // 128-row tiles per dim of unified matrix
#define NSUB 384              // partial-sum slots (fp32) — fully covered, no memset needed
#define NBLK (NTT * (NTT + 1) / 2)   // 18528 = 8 * 2316
#define LAM 1.69864368f       // sqrt(log2(e)/TAU); gram acc = sim*log2e/tau directly

__device__ __forceinline__ unsigned short f2bf(float f) {
    unsigned int x = __builtin_bit_cast(unsigned int, f);
    x += 0x7fffu + ((x >> 16) & 1u);
    return (unsigned short)(x >> 16);
}

// manual OCP e4m3fn cast, RNE in normal range, step-round in denormal range
__device__ __forceinline__ unsigned char f2e4m3(float f) {
    unsigned int u = __builtin_bit_cast(unsigned int, f);
    unsigned int s = (u >> 24) & 0x80u;
    float af = fabsf(f);
    if (af >= 464.f) return (unsigned char)(s | 0x7Eu);      // saturate to 448
    if (af < 0.015625f) {                                    // denormal: step 2^-9
        unsigned int q = (unsigned int)(af * 512.f + 0.5f);
        return (unsigned char)(s | q);
    }
    int e = (int)((u >> 23) & 0xffu) - 127;
    unsigned int mant = u & 0x7fffffu;
    unsigned int val = (unsigned int)((e + 7) << 3) | (mant >> 20);
    unsigned int rem = mant & 0xfffffu;
    val += (rem > 0x80000u) || (rem == 0x80000u && (val & 1u));
    return (unsigned char)(s | val);
}

// sum over each 16-lane group via 4 DPP adds — pure VALU, zero LDS-pipe traffic.
__device__ __forceinline__ float row16_sum(float x) {
    int v;
    v = __builtin_amdgcn_update_dpp(0, __builtin_bit_cast(int, x), 0xB1, 0xF, 0xF, true);
    x += __builtin_bit_cast(float, v);
    v = __builtin_amdgcn_update_dpp(0, __builtin_bit_cast(int, x), 0x4E, 0xF, 0xF, true);
    x += __builtin_bit_cast(float, v);
    v = __builtin_amdgcn_update_dpp(0, __builtin_bit_cast(int, x), 0x141, 0xF, 0xF, true);
    x += __builtin_bit_cast(float, v);
    v = __builtin_amdgcn_update_dpp(0, __builtin_bit_cast(int, x), 0x140, 0xF, 0xF, true);
    x += __builtin_bit_cast(float, v);
    return x;
}

// load 8 consecutive f32 and round-to-nearest-even pack into bf16x8 (verified in R11/R12)
__device__ __forceinline__ bf16x8 cvt8(const float* __restrict__ p) {
    float4 a = *(const float4*)p;
    float4 b = *(const float4*)(p + 4);
    union { unsigned int i[4]; bf16x8 v; } u;
    u.i[0] = ((unsigned int)f2bf(a.y) << 16) | f2bf(a.x);
    u.i[1] = ((unsigned int)f2bf(a.w) << 16) | f2bf(a.z);
    u.i[2] = ((unsigned int)f2bf(b.y) << 16) | f2bf(b.x);
    u.i[3] = ((unsigned int)f2bf(b.w) << 16) | f2bf(b.z);
    return u.v;
}

// ---------- both W transposes in one launch: grid (HD, 2) ----------
__global__ __launch_bounds__(256) void transpose_cast_kernel(const float* __restrict__ W1,
                                                             const float* __restrict__ W2,
                                                             unsigned short* __restrict__ W1t,
                                                             unsigned short* __restrict__ W2t) {
    const float* W = blockIdx.y ? W2 : W1;
    unsigned short* Wt = blockIdx.y ? W2t : W1t;
    int n = blockIdx.x;
    int k = threadIdx.x;
    Wt[n * HD + k] = f2bf(W[k * HD + n]);
}

// ---------- projA: z (f32, cast in-register) @ W1t^T + b1, ELU -> t (bf16). grid (192, 2) ----------
__global__ __launch_bounds__(256) void projA_kernel(const float* __restrict__ z1,
                                                    const float* __restrict__ z2,
                                                    const unsigned short* __restrict__ W1t,
                                                    const float* __restrict__ b1,
                                                    unsigned short* __restrict__ t1,
                                                    unsigned short* __restrict__ t2) {
    const float* A = blockIdx.y ? z2 : z1;
    unsigned short* C = blockIdx.y ? t2 : t1;
    const int lane = threadIdx.x & 63;
    const int wave = threadIdx.x >> 6;
    const int row0 = blockIdx.x * 64;
    const int col0 = wave * 64;
    const int lr = lane & 15, lk = lane >> 4;

    f32x4 acc[4][4] = {};
    const unsigned short* Bb = W1t + (size_t)(col0 + lr) * HD + lk * 8;
#pragma unroll
    for (int k0 = 0; k0 < HD; k0 += 32) {
        bf16x8 af[4], bfr[4];
#pragma unroll
        for (int m = 0; m < 4; ++m)
            af[m] = cvt8(A + (size_t)(row0 + m * 16 + lr) * HD + k0 + lk * 8);
#pragma unroll
        for (int n = 0; n < 4; ++n) bfr[n] = *(const bf16x8*)(Bb + n * 16 * HD + k0);
#pragma unroll
        for (int m = 0; m < 4; ++m)
#pragma unroll
            for (int n = 0; n < 4; ++n)
                acc[m][n] = __builtin_amdgcn_mfma_f32_16x16x32_bf16(af[m], bfr[n], acc[m][n], 0, 0, 0);
    }
#pragma unroll
    for (int m = 0; m < 4; ++m) {
#pragma unroll
        for (int n = 0; n < 4; ++n) {
            int col = col0 + n * 16 + lr;
            float b = b1[col];
#pragma unroll
            for (int r = 0; r < 4; ++r) {
                int row = row0 + m * 16 + lk * 4 + r;
                float v = acc[m][n][r] + b;
                v = v > 0.f ? v : expm1f(v);
                C[(size_t)row * HD + col] = f2bf(v);
            }
        }
    }
}

// ---------- projB: t (bf16) @ W2t^T + b2 -> h (f32). grid (192, 2) ----------
__global__ __launch_bounds__(256) void projB_kernel(const unsigned short* __restrict__ t1,
                                                    const unsigned short* __restrict__ t2,
                                                    const unsigned short* __restrict__ W2t,
                                                    const float* __restrict__ b2,
                                                    float* __restrict__ h1,
                                                    float* __restrict__ h2) {
    const unsigned short* A = blockIdx.y ? t2 : t1;
    float* C = blockIdx.y ? h2 : h1;
    const int lane = threadIdx.x & 63;
    const int wave = threadIdx.x >> 6;
    const int row0 = blockIdx.x * 64;
    const int col0 = wave * 64;
    const int lr = lane & 15, lk = lane >> 4;

    f32x4 acc[4][4] = {};
    const unsigned short* Ab = A + (size_t)(row0 + lr) * HD + lk * 8;
    const unsigned short* Bb = W2t + (size_t)(col0 + lr) * HD + lk * 8;
#pragma unroll
    for (int k0 = 0; k0 < HD; k0 += 32) {
        bf16x8 af[4], bfr[4];
#pragma unroll
        for (int m = 0; m < 4; ++m) af[m] = *(const bf16x8*)(Ab + m * 16 * HD + k0);
#pragma unroll
        for (int n = 0; n < 4; ++n) bfr[n] = *(const bf16x8*)(Bb + n * 16 * HD + k0);
#pragma unroll
        for (int m = 0; m < 4; ++m)
#pragma unroll
            for (int n = 0; n < 4; ++n)
                acc[m][n] = __builtin_amdgcn_mfma_f32_16x16x32_bf16(af[m], bfr[n], acc[m][n], 0, 0, 0);
    }
#pragma unroll
    for (int m = 0; m < 4; ++m) {
#pragma unroll
        for (int n = 0; n < 4; ++n) {
            int col = col0 + n * 16 + lr;
            float b = b2[col];
#pragma unroll
            for (int r = 0; r < 4; ++r) {
                int row = row0 + m * 16 + lk * 4 + r;
                C[(size_t)row * HD + col] = acc[m][n][r] + b;
            }
        }
    }
}

// ---------- normalize rows (fp32) -> fp8 e4m3 (LAM-scaled) into unified buffer + dvec ----------
// nU8 layout: the two 8B halves of every 16B chunk are SWAPPED for rows with bit3 set
// (store addr ^= ((row>>3)&1)<<3) — pre-bakes the LDS bank half-swap for conflict-free b64 reads.
__global__ __launch_bounds__(256) void norm_diag_kernel(const float* __restrict__ h1,
                                                        const float* __restrict__ h2,
                                                        unsigned char* __restrict__ n1,
                                                        unsigned char* __restrict__ n2,
                                                        float* __restrict__ dvec) {
    const int lane = threadIdx.x & 63;
    const int wave = threadIdx.x >> 6;
    const int row = blockIdx.x * 4 + wave;
    const float4 a = *(const float4*)(h1 + (size_t)row * HD + lane * 4);
    const float4 b = *(const float4*)(h2 + (size_t)row * HD + lane * 4);
    float sa = a.x * a.x + a.y * a.y + a.z * a.z + a.w * a.w;
    float sb = b.x * b.x + b.y * b.y + b.z * b.z + b.w * b.w;
    float sab = a.x * b.x + a.y * b.y + a.z * b.z + a.w * b.w;
#pragma unroll
    for (int m = 32; m; m >>= 1) {
        sa += __shfl_xor(sa, m);
        sb += __shfl_xor(sb, m);
        sab += __shfl_xor(sab, m);
    }
    float na = sqrtf(sa); na = na > 1e-12f ? na : 1e-12f;
    float nb = sqrtf(sb); nb = nb > 1e-12f ? nb : 1e-12f;
    float ia = 1.f / na, ib = 1.f / nb;
    float sca = ia * LAM, scb = ib * LAM;
    uchar4 q1, q2;
    q1.x = f2e4m3(a.x * sca); q1.y = f2e4m3(a.y * sca); q1.z = f2e4m3(a.z * sca); q1.w = f2e4m3(a.w * sca);
    q2.x = f2e4m3(b.x * scb); q2.y = f2e4m3(b.y * scb); q2.z = f2e4m3(b.z * scb); q2.w = f2e4m3(b.w * scb);
    const int sw = ((row >> 3) & 1) << 3;                    // half-swap by row bit3
    *(uchar4*)(n1 + (size_t)row * HD + ((lane * 4) ^ sw)) = q1;
    *(uchar4*)(n2 + (size_t)row * HD + ((lane * 4) ^ sw)) = q2;
    if (lane == 0) dvec[row] = sab * ia * ib * (1.f / TAU);
}

// ---------- unified symmetric Gram (fp8): upper-tri 128x128 tiles of exp2(M@M^T) ----------
// R15 gram verbatim (plateau structure: 201us, n=9) with ONE change: the 128 exp2f calls
// use raw v_exp_f32 (__builtin_amdgcn_exp2f) — 1 issue slot each, vs libm's multi-inst
// expansion — and the n-sums pair up before the DPP tree. MFMA+VALU issue was ~96% of the
// SIMD port; this is a pure VALU diet with no structural risk.
__global__ __launch_bounds__(256, 2) void gram_kernel(const unsigned char* __restrict__ nU8,
                                                      float* __restrict__ RPART) {
    __shared__ __align__(16) unsigned char lA[128 * 256];  // 32KB
    __shared__ __align__(16) unsigned char lB[128 * 256];  // 32KB

    const int bid = blockIdx.x;
    const int t0 = (bid & 7) * (NBLK / 8) + (bid >> 3);
    int i = (int)((385.f - sqrtf((float)(385 * 385 - 8 * t0))) * 0.5f);
    if (i < 0) i = 0;
    if (i > NTT - 1) i = NTT - 1;
    while (i > 0 && i * NTT - i * (i - 1) / 2 > t0) --i;
    while ((i + 1) * NTT - (i + 1) * i / 2 <= t0) ++i;
    const int j = i + (t0 - (i * NTT - i * (i - 1) / 2));
    const bool diag = (i == j);

    const unsigned char* X = nU8 + (size_t)i * 128 * HD;
    const unsigned char* Y = nU8 + (size_t)j * 128 * HD;

    const int t = threadIdx.x;
    const int lane = t & 63;
    const int wave = t >> 6;
    const int wr = wave >> 1, wc = wave & 1;      // 2x2 wave grid; wave tile 64x64
    const int lr = lane & 15, lk = lane >> 4;

    {
        const int rbase = t >> 4;                              // 0..15
        const int schunk = (t & 15) ^ rbase;                   // pre-swizzled source slot
        const unsigned char* gx = X + rbase * 256 + schunk * 16;
        const unsigned char* gy = Y + rbase * 256 + schunk * 16;
#pragma unroll
        for (int c = 0; c < 8; ++c) {
            __builtin_amdgcn_global_load_lds(
                (const __attribute__((address_space(1))) unsigned int*)(gx + c * 4096),
                (__attribute__((address_space(3))) unsigned int*)(&lA[c * 4096 + t * 16]),
                16, 0, 0);
        }
        if (!diag) {
#pragma unroll
            for (int c = 0; c < 8; ++c) {
                __builtin_amdgcn_global_load_lds(
                    (const __attribute__((address_space(1))) unsigned int*)(gy + c * 4096),
                    (__attribute__((address_space(3))) unsigned int*)(&lB[c * 4096 + t * 16]),
                    16, 0, 0);
            }
        }
    }
    __syncthreads();   // the ONLY barrier in this kernel

    f32x4 acc[4][4] = {};
    const int hswap = (lr >> 3) & 1;
    const unsigned char* sA = lA + (size_t)(wr * 64 + lr) * 256 + ((lk & 1) ^ hswap) * 8;
    const unsigned char* sBb = (diag ? lA : lB);
    const unsigned char* sB = sBb + (size_t)(wc * 64 + lr) * 256 + ((lk & 1) ^ hswap) * 8;

    // hoisted per-ks read addresses (compile-time indexed -> registers)
    const unsigned char* pA[8];
    const unsigned char* pB[8];
#pragma unroll
    for (int ks = 0; ks < 8; ++ks) {
        const int chnk = ((2 * ks + (lk >> 1)) ^ lr) * 16;
        pA[ks] = sA + chnk;
        pB[ks] = sB + chnk;
    }

#pragma unroll
    for (int ks = 0; ks < 8; ++ks) {
        long af[4], bfr[4];
#pragma unroll
        for (int m = 0; m < 4; ++m)
            af[m] = *(const long*)(pA[ks] + m * 16 * 256);
#pragma unroll
        for (int n = 0; n < 4; ++n)
            bfr[n] = *(const long*)(pB[ks] + n * 16 * 256);
#pragma unroll
        for (int m = 0; m < 4; ++m)
#pragma unroll
            for (int n = 0; n < 4; ++n)
                acc[m][n] = __builtin_amdgcn_mfma_f32_16x16x32_fp8_fp8(af[m], bfr[n], acc[m][n], 0, 0, 0);
    }

    // exp2 via raw v_exp_f32 (1 issue slot; |arg| <= 2.89 so no edge cases matter)
#pragma unroll
    for (int m = 0; m < 4; ++m)
#pragma unroll
        for (int n = 0; n < 4; ++n)
#pragma unroll
            for (int r = 0; r < 4; ++r)
                acc[m][n][r] = __builtin_amdgcn_exp2f(acc[m][n][r]);

    // rowsum partials (DPP, VALU-only; paired adds)
    {
        float* dst = RPART + (size_t)(2 * j + wc) * NU + i * 128 + wr * 64;
#pragma unroll
        for (int m = 0; m < 4; ++m) {
            f32x4 s01 = acc[m][0] + acc[m][1];
            f32x4 s23 = acc[m][2] + acc[m][3];
            f32x4 s = s01 + s23;
#pragma unroll
            for (int r = 0; r < 4; ++r) {
                float rs = row16_sum(s[r]);
                if (lr == 0) dst[m * 16 + lk * 4 + r] = rs;
            }
        }
    }
    // colsum partials (off-diag)
    if (!diag) {
        float* dst = RPART + (size_t)(2 * i + wr) * NU + j * 128 + wc * 64;
#pragma unroll
        for (int n = 0; n < 4; ++n) {
            f32x4 s01 = acc[0][n] + acc[1][n];
            f32x4 s23 = acc[2][n] + acc[3][n];
            f32x4 s = s01 + s23;
            float cs = (s[0] + s[1]) + (s[2] + s[3]);
            cs += __shfl_xor(cs, 16);
            cs += __shfl_xor(cs, 32);
            if (lk == 0) dst[n * 16 + lr] = cs;
        }
    }
}

// ---------- fused reduce + loss (verified R11/R12): S terms from RPART, log-loss, partials ----------
__global__ __launch_bounds__(128) void loss_sum_kernel(const float* __restrict__ RPART,
                                                       const float* __restrict__ dvec,
                                                       float* __restrict__ partial) {
    const int i = blockIdx.x * 128 + threadIdx.x;
    float s1 = 0.f, s2 = 0.f;
#pragma unroll 8
    for (int p = 0; p < NSUB; ++p) {
        s1 += RPART[(size_t)p * NU + i];
        s2 += RPART[(size_t)p * NU + NR + i];
    }
    const float e2 = 7.389056099f;  // exp(1/tau)
    float v = 0.5f * (logf(s1 - e2) + logf(s2 - e2)) - dvec[i];
#pragma unroll
    for (int m = 32; m; m >>= 1) v += __shfl_xor(v, m);
    __shared__ float wsum[2];
    if ((threadIdx.x & 63) == 0) wsum[threadIdx.x >> 6] = v;
    __syncthreads();
    if (threadIdx.x == 0) partial[blockIdx.x] = wsum[0] + wsum[1];
}

__global__ __launch_bounds__(128) void loss_final_kernel(const float* __restrict__ partial,
                                                         float* __restrict__ out, int nb) {
    float s = 0.f;
    for (int i = threadIdx.x; i < nb; i += 128) s += partial[i];
#pragma unroll
    for (int m = 32; m; m >>= 1) s += __shfl_xor(s, m);
    __shared__ float wsum[2];
    if ((threadIdx.x & 63) == 0) wsum[threadIdx.x >> 6] = s;
    __syncthreads();
    if (threadIdx.x == 0) out[0] = (wsum[0] + wsum[1]) * (1.f / (float)NR);
}

extern "C" void kernel_launch(void* const* d_in, const int* in_sizes, int n_in,
                              void* d_out, int out_size, void* d_ws, size_t ws_size,
                              hipStream_t stream) {
    const float* z1 = (const float*)d_in[0];
    const float* z2 = (const float*)d_in[1];
    const float* W1 = (const float*)d_in[2];
    const float* b1 = (const float*)d_in[3];
    const float* W2 = (const float*)d_in[4];
    const float* b2 = (const float*)d_in[5];

    char* ws = (char*)d_ws;
    size_t off = 0;
    auto alloc = [&](size_t bytes) {
        void* p = ws + off;
        off += (bytes + 255) & ~(size_t)255;
        return p;
    };
    const size_t NH2 = (size_t)NR * HD * 2;  // bf16 matrix bytes (6.29 MB)
    // Dead-by-gram-time prefix (t1,t2,W,h1,h2 = 38.01 MB) is aliased by RPART (37.75 MB).
    unsigned short* t1 = (unsigned short*)alloc(NH2);
    unsigned short* t2 = (unsigned short*)alloc(NH2);
    unsigned short* W1t = (unsigned short*)alloc(HD * HD * 2);
    unsigned short* W2t = (unsigned short*)alloc(HD * HD * 2);
    float* h1 = (float*)alloc((size_t)NR * HD * 4);
    float* h2 = (float*)alloc((size_t)NR * HD * 4);
    unsigned char* nU = (unsigned char*)alloc((size_t)NU * HD);   // fp8, LAM-scaled (live)
    float* dvec = (float*)alloc(NR * 4);                          // live
    float* partial = (float*)alloc(96 * 4);                       // live
    float* RPART = (float*)ws;  // 384*24576*4 = 37,748,736 B < nU offset (38,010,880)

    transpose_cast_kernel<<<dim3(HD, 2), 256, 0, stream>>>(W1, W2, W1t, W2t);

    projA_kernel<<<dim3(NR / 64, 2), 256, 0, stream>>>(z1, z2, W1t, b1, t1, t2);
    projB_kernel<<<dim3(NR / 64, 2), 256, 0, stream>>>(t1, t2, W2t, b2, h1, h2);

    norm_diag_kernel<<<NR / 4, 256, 0, stream>>>(h1, h2, nU, nU + (size_t)NR * HD, dvec);

    gram_kernel<<<NBLK, 256, 0, stream>>>(nU, RPART);

    loss_sum_kernel<<<NR / 128, 128, 0, stream>>>(RPART, dvec, partial);
    loss_final_kernel<<<1, 128, 0, stream>>>(partial, (float*)d_out, NR / 128);
}